// Round 2
// baseline (683.793 us; speedup 1.0000x reference)
//
#include <hip/hip_runtime.h>
#include <math.h>

#define BIGD 1e10f
#define NPTS 20
#define BPB  4   // batch items per block: one per wave; waves fully independent

typedef float f4 __attribute__((ext_vector_type(4)));

// Wave-synchronous LDS fence: waves are lockstep on CDNA, so ordering the
// LDS ops (lgkmcnt) + pinning the scheduler is sufficient -- no s_barrier.
__device__ __forceinline__ void wave_lds_fence() {
    asm volatile("s_waitcnt lgkmcnt(0)" ::: "memory");
    __builtin_amdgcn_sched_barrier(0);
}

__global__ __launch_bounds__(256) void spf_kernel(
    const float* __restrict__ points,    // [B,20,3]
    const float* __restrict__ mask,      // [B,20]
    const float* __restrict__ W_rel,     // [3,64]
    const float* __restrict__ b_rel,     // [64]
    const float* __restrict__ W_dist,    // [1,64]
    const float* __restrict__ b_dist,    // [64]
    const float* __restrict__ emb_count, // [50,64]
    const float* __restrict__ W_den,     // [1,64]
    const float* __restrict__ b_den,     // [64]
    float* __restrict__ out,             // [B,20,256]
    int B)
{
    const int w    = threadIdx.x >> 6;   // wave id 0..3 -> batch item
    const int lane = threadIdx.x & 63;
    const int b    = blockIdx.x * BPB + w;
    if (b >= B) return;                  // safe: no barriers anywhere

    // Packed per-wave LDS: one b128 broadcast read replaces 4 scalar reads.
    __shared__ __align__(16) f4    sPM[BPB][NPTS];   // {x, y, z, m}
    __shared__ __align__(16) f4    sRC[BPB][NPTS];   // {rx, ry, rz, cdist}
    __shared__          float sDen[BPB][NPTS];

    // Stage: lane i (0..19) loads point i + mask i, writes packed f4.
    // 20 lanes x 12B points = 240B contiguous per wave -> coalesces fine.
    if (lane < NPTS) {
        const float* pp = points + (size_t)b * (NPTS * 3) + lane * 3;
        f4 q;
        q.x = pp[0]; q.y = pp[1]; q.z = pp[2];
        q.w = mask[(size_t)b * NPTS + lane];
        sPM[w][lane] = q;
    }
    wave_lds_fence();

    // Centroid + n_valid: all lanes redundantly reduce 20 rows (20 b128 broadcasts).
    float sm = 0.f, cx = 0.f, cy = 0.f, cz = 0.f;
#pragma unroll
    for (int i = 0; i < NPTS; ++i) {
        const f4 q = sPM[w][i];
        sm += q.w;
        cx = fmaf(q.w, q.x, cx);
        cy = fmaf(q.w, q.y, cy);
        cz = fmaf(q.w, q.z, cz);
    }
    const float nvf = fmaxf(sm, 1.0f);   // clip(n_valid, 1)
    cx /= nvf; cy /= nvf; cz /= nvf;
    const int nv  = (int)(sm + 0.5f);    // exact: mask is 0.0/1.0
    const int idx = (int)(nvf + 0.5f);   // emb_count row, 1..20

    // Lanes 0..19: density (top-3 nearest valid) + rel + cdist, packed writes.
    if (lane < NPTS) {
        const f4 me = sPM[w][lane];
        const float mi = me.w;
        float b0 = BIGD, b1 = BIGD, b2 = BIGD;   // ascending 3 smallest
#pragma unroll
        for (int j = 0; j < NPTS; ++j) {
            const f4 qj = sPM[w][j];
            const float dx = me.x - qj.x;
            const float dy = me.y - qj.y;
            const float dz = me.z - qj.z;
            const float d2 = dx * dx + dy * dy + dz * dz;
            float d = sqrtf(fmaxf(d2, 1e-12f));
            const bool valid = (j != lane) && (mi > 0.f) && (qj.w > 0.f);
            d = valid ? d : BIGD;
            if (d < b0)      { b2 = b1; b1 = b0; b0 = d; }
            else if (d < b1) { b2 = b1; b1 = d; }
            else if (d < b2) { b2 = d; }
        }
        int k = min(3, nv - 1);
        k = max(k, 1);
        float s = b0;
        if (k > 1) s += b1;
        if (k > 2) s += b2;
        const float dens = s / (float)k;
        sDen[w][lane] = ((mi > 0.f) && (nv > 1)) ? dens : 0.f;

        f4 rc;
        rc.x = me.x - cx; rc.y = me.y - cy; rc.z = me.z - cz;
        rc.w = sqrtf(rc.x * rc.x + rc.y * rc.y + rc.z * rc.z);
        sRC[w][lane] = rc;
    }
    wave_lds_fence();

    // Output: lane g owns 4 adjacent columns; per n: 1 b128 + 1 b32 broadcast,
    // 16 FMA, one 1024B-contiguous wave store (plain store -- fill proves this
    // path hits 6.3 TB/s).
    const int region = lane >> 4;    // 0:rel_f 1:dist_f 2:count_f 3:den_f
    const int cq     = lane & 15;

    f4 w0 = {0,0,0,0}, w1 = {0,0,0,0}, w2 = {0,0,0,0};
    f4 wd = {0,0,0,0}, bb = {0,0,0,0};
    if (region == 0) {
        w0 = ((const f4*)(W_rel +   0))[cq];
        w1 = ((const f4*)(W_rel +  64))[cq];
        w2 = ((const f4*)(W_rel + 128))[cq];
        bb = ((const f4*)b_rel)[cq];
    } else if (region == 1) {
        wd = ((const f4*)W_dist)[cq];
        bb = ((const f4*)b_dist)[cq];
    } else if (region == 2) {
        bb = ((const f4*)(emb_count + (size_t)idx * 64))[cq];
    } else {
        wd = ((const f4*)W_den)[cq];
        bb = ((const f4*)b_den)[cq];
    }
    const bool use_cd = (region == 1);

    f4* __restrict__ outv = (f4*)(out + (size_t)b * (NPTS * 256));
#pragma unroll
    for (int n = 0; n < NPTS; ++n) {
        const f4 rc = sRC[w][n];        // broadcast b128
        const float dn = sDen[w][n];    // broadcast b32
        const float sc = use_cd ? rc.w : dn;
        f4 v;
        v.x = fmaf(rc.x, w0.x, fmaf(rc.y, w1.x, fmaf(rc.z, w2.x, fmaf(sc, wd.x, bb.x))));
        v.y = fmaf(rc.x, w0.y, fmaf(rc.y, w1.y, fmaf(rc.z, w2.y, fmaf(sc, wd.y, bb.y))));
        v.z = fmaf(rc.x, w0.z, fmaf(rc.y, w1.z, fmaf(rc.z, w2.z, fmaf(sc, wd.z, bb.z))));
        v.w = fmaf(rc.x, w0.w, fmaf(rc.y, w1.w, fmaf(rc.z, w2.w, fmaf(sc, wd.w, bb.w))));
        outv[n * 64 + lane] = v;
    }
}

extern "C" void kernel_launch(void* const* d_in, const int* in_sizes, int n_in,
                              void* d_out, int out_size, void* d_ws, size_t ws_size,
                              hipStream_t stream) {
    const float* points    = (const float*)d_in[0];
    const float* mask      = (const float*)d_in[1];
    const float* W_rel     = (const float*)d_in[2];
    const float* b_rel     = (const float*)d_in[3];
    const float* W_dist    = (const float*)d_in[4];
    const float* b_dist    = (const float*)d_in[5];
    const float* emb_count = (const float*)d_in[6];
    const float* W_den     = (const float*)d_in[7];
    const float* b_den     = (const float*)d_in[8];
    float* out             = (float*)d_out;

    const int B    = in_sizes[0] / (NPTS * 3);   // 32768
    const int grid = (B + BPB - 1) / BPB;        // 8192
    spf_kernel<<<grid, 256, 0, stream>>>(points, mask, W_rel, b_rel, W_dist, b_dist,
                                         emb_count, W_den, b_den, out, B);
}